// Round 7
// baseline (47.119 us; speedup 1.0000x reference)
//
#include <hip/hip_runtime.h>

// ---------------------------------------------------------------------------
// Depthwise 1-D full correlation, per (batch, filter):
//   out[t] = sum_s y[s] * w[2047 + s - t],   t, s in [0, 4096)
// Slab per (b,f) in ws (ushort units):
//   [0,8448)      y-region: y[s] at 2048+s, zero pads [0,2048) & [6144,8448)
//   [8448,12544)  w[4096]
//   [12544,20736) out f32[4096]
// K0: transpose/convert X -> slabs (y, w, zero pads)
// K1: MFMA; waves = 8h x 4p split; y read GLOBAL (L2-resident slab); A (w)
//     from LDS (WA/WB parity copies, verified path); pairwise exchange.
// K2: 32x32 transpose out-regions -> out[b][t][f]; one writer per line.
// All kernels: b = bid&31 so bid%8==b%8 -> slab pipeline XCD-local.
// ---------------------------------------------------------------------------

#define T_LEN 4096
#define F_CH  32
#define SLAB_US 20736
#define Y_OFF 0
#define W_OFF 8448
#define O_OFF 12544

// K1 LDS (ushort units)
#define WAo 0                 // WA[16+i] = w[i]
#define WBo 4144              // WB[15+i] = w[i]
#define LDS_US 8288           // 16576 B; exchange overlay needs 8192 us

using short8 = __attribute__((ext_vector_type(8))) short;
using f32x4  = __attribute__((ext_vector_type(4))) float;
using uint4v = __attribute__((ext_vector_type(4))) unsigned int;

__device__ __forceinline__ unsigned short bf16b(float x) {
    unsigned int u = __float_as_uint(x);
    u += 0x7FFFu + ((u >> 16) & 1u);      // RNE
    return (unsigned short)(u >> 16);
}

// exchange swizzle within a 256-dword h-block (R5-verified)
#define RSWZ(j)  ((j) ^ ((((j) >> 4) & 7) << 2))

// ---------------------------------------------------------------------------
__global__ __launch_bounds__(256)
void k0_stage(const float* __restrict__ X, unsigned short* __restrict__ ws) {
    __shared__ unsigned short tile[64 * 130];
    const int tid = threadIdx.x;
    const int b    = blockIdx.x & 31;            // bid%8 == b%8 (XCD-local)
    const int tpos = blockIdx.x >> 5;            // 0..31
    const int s0   = tpos << 7;                  // 128-row stripe

    unsigned short* wsb = ws + (size_t)b * 32 * SLAB_US;
    const f32x4 zf = (f32x4)0.0f;

    // ---- zero y-region pads (1/32 per stripe-block, all 32 slabs of b) ----
    {   // lpad: 32 f x 8 uint4 -> one per thread
        int f = tid >> 3, k = tid & 7;
        *(f32x4*)(wsb + (size_t)f * SLAB_US + tpos * 64 + 8 * k) = zf;
    }
    for (int i = tid; i < 288; i += 256) {       // rpad: 32 f x 9 uint4
        int f = i / 9, k = i - 9 * f;
        *(f32x4*)(wsb + (size_t)f * SLAB_US + 6144 + tpos * 72 + 8 * k) = zf;
    }

    // ---- transpose 128 x 64 tile ----
    const float* xb = X + ((size_t)b * T_LEN + s0) * 64;
#pragma unroll
    for (int i = 0; i < 8; ++i) {
        int d4 = 4 * (tid + 256 * i);
        int row = d4 >> 6, c0 = d4 & 63;
        f32x4 xv = *(const f32x4*)(xb + (size_t)row * 64 + c0);
#pragma unroll
        for (int k = 0; k < 4; ++k)
            tile[(c0 + k) * 130 + row] = bf16b(xv[k]);
    }
    __syncthreads();

    // ---- write y & w slabs (dword stores, coalesced) ----
#pragma unroll
    for (int i = 0; i < 16; ++i) {
        int dw = tid + 256 * i;                  // 0..4095
        int c = dw >> 6, j0 = (dw & 63) * 2;
        unsigned int two = *(const unsigned int*)(tile + c * 130 + j0);
        unsigned short* slab;
        int off;
        if (c < 32) { slab = wsb + (size_t)c * SLAB_US; off = 2048 + s0 + j0; }
        else { slab = wsb + (size_t)(c - 32) * SLAB_US; off = W_OFF + s0 + j0; }
        *(unsigned int*)(slab + off) = two;
    }
}

// ---------------------------------------------------------------------------
__global__ __launch_bounds__(256, 4)
void corr1d_mfma_kernel(unsigned short* __restrict__ ws) {
    __shared__ __align__(16) unsigned short lds[LDS_US];
    const int tid = threadIdx.x;
    const int b = blockIdx.x & 31;               // bid%8 == b%8 (XCD-local)
    const int f = blockIdx.x >> 5;
    unsigned short* slab = ws + (size_t)(b * 32 + f) * SLAB_US;

    // ---- zero W pad regions ----
    f32x4 z4 = (f32x4)0.0f;
    if (tid < 2)       *(f32x4*)(lds + WAo + 8 * tid) = z4;              // WA [0,16)
    else if (tid < 6)  *(f32x4*)(lds + WAo + 4112 + 8 * (tid - 2)) = z4; // WA [4112,4144)
    else if (tid == 6) {
        *(f32x4*)(lds + WBo) = z4;                                       // WB [0,8)
        for (int i = 8; i < 14; ++i) lds[WBo + i] = 0;                   // WB [8,14)
    } else if (tid >= 8 && tid < 12)
        *(f32x4*)(lds + WBo + 4112 + 8 * (tid - 8)) = z4;                // WB [4112,4144)

    // ---- stage WA, build WB (+1 shift) from registers ----
    const uint4v* sv = (const uint4v*)(slab + W_OFF);
    unsigned int* wb32 = (unsigned int*)(lds + WBo);
#pragma unroll
    for (int r = 0; r < 2; ++r) {
        int c = tid + 256 * r;                   // 0..511
        uint4v vw = sv[c];                       // w[8c .. 8c+7]
        *(uint4v*)(lds + WAo + 16 + 8 * c) = vw;
        unsigned int wm1 = (c == 0) ? 0u
                         : (unsigned int)slab[W_OFF + 8 * c - 1];
        unsigned int v0 = vw[0], v1 = vw[1], v2 = vw[2], v3 = vw[3];
        wb32[7 + 4 * c + 0] = (wm1 & 0xFFFFu) | (v0 << 16);
        wb32[7 + 4 * c + 1] = (v0 >> 16) | (v1 << 16);
        wb32[7 + 4 * c + 2] = (v1 >> 16) | (v2 << 16);
        wb32[7 + 4 * c + 3] = (v2 >> 16) | (v3 << 16);
        if (c == 511) wb32[2055] = (v3 >> 16);   // (w[4095], 0)
    }
    __syncthreads();

    // ---- compute: wave = 8 h x 4 passes ----
    const int lane = tid & 63;
    const int wv   = tid >> 6;                   // 0..3
    const int nn   = lane & 15;
    const int q    = lane >> 4;
    const int ko   = q << 3;
    const int H    = (wv >> 1) << 3;             // h-base: 0 or 8
    const int writer = wv & 1;                   // odd: passes 0-3 (+extra)
    const int P0   = writer ? 0 : 4;

    f32x4 acc[8];
#pragma unroll
    for (int h = 0; h < 8; ++h) acc[h] = (f32x4)0.0f;

    short8 cache[8];

    const int tiOdd = nn & 1;
    const unsigned short* wbase = tiOdd ? &lds[WAo] : &lds[WBo];
    const int aoff0 = (tiOdd ? 15 : 14) + ko - nn;           // even, >= 0
    const int yoff0 = 16 * nn + ko;
    const unsigned short* yg = slab;             // y-region base (GLOBAL)

    for (int pp = 0; pp < 4; ++pp) {
        const int p = P0 + pp;
        const unsigned short* yb = yg + (yoff0 + 32 * p + 256 * H);
        const unsigned int* abase =
            (const unsigned int*)(wbase + (aoff0 + 32 * p));

#pragma unroll
        for (int s = 0; s < 8; ++s)
            cache[s] = *(const short8*)(yb + 256 * s);

#pragma unroll
        for (int M = 0; M < 16; ++M) {
            unsigned int a0 = abase[128 * M + 0];
            unsigned int a1 = abase[128 * M + 1];
            unsigned int a2 = abase[128 * M + 2];
            unsigned int a3 = abase[128 * M + 3];
            uint4v av = {a0, a1, a2, a3};
            short8 af = __builtin_bit_cast(short8, av);
            __builtin_amdgcn_s_setprio(1);
#pragma unroll
            for (int h = 0; h < 8; ++h)
                acc[h] = __builtin_amdgcn_mfma_f32_16x16x32_bf16(
                    af, cache[(h + M) & 7], acc[h], 0, 0, 0);
            __builtin_amdgcn_s_setprio(0);
            cache[M & 7] = *(const short8*)(yb + 256 * (M + 8));
        }

        if (p == 0) {                            // extra M=16 (d=+128 tail)
            unsigned int a0 = abase[2048];
            unsigned int a1 = abase[2049];
            unsigned int a2 = abase[2050];
            unsigned int a3 = abase[2051];
            uint4v av = {a0, a1, a2, a3};
            short8 af = __builtin_bit_cast(short8, av);
            __builtin_amdgcn_s_setprio(1);
#pragma unroll
            for (int h = 0; h < 8; ++h)
                acc[h] = __builtin_amdgcn_mfma_f32_16x16x32_bf16(
                    af, cache[h], acc[h], 0, 0, 0);
            __builtin_amdgcn_s_setprio(0);
        }
    }

    // ---- pairwise exchange (writers: wv odd) + final store ----
    __syncthreads();
    float* exch = (float*)lds;
    const int jswz = RSWZ(16 * nn + 4 * q);

    if (writer) {
        float* dst = exch + (wv >> 1) * 2048;
#pragma unroll
        for (int h = 0; h < 8; ++h)
            *(f32x4*)(dst + 256 * h + jswz) = acc[h];
    }
    __syncthreads();
    if (!writer) {
        const float* src = exch + (wv >> 1) * 2048;
        float* outf = (float*)(slab + O_OFF);
#pragma unroll
        for (int h = 0; h < 8; ++h) {
            f32x4 v = *(const f32x4*)(src + 256 * h + jswz);
            v += acc[h];
            *(f32x4*)(outf + 256 * (H + h) + 16 * nn + 4 * q) = v;
        }
    }
}

// ---------------------------------------------------------------------------
__global__ __launch_bounds__(256)
void k2_out(const unsigned short* __restrict__ ws, float* __restrict__ out) {
    __shared__ float tile[32][33];
    const int blk = blockIdx.x;
    const int b  = blk & 31;                     // bid%8 == b%8 (XCD-local)
    const int t0 = (blk >> 5) << 5;
    const int a  = threadIdx.x >> 5;
    const int j  = threadIdx.x & 31;

#pragma unroll
    for (int ff = a; ff < 32; ff += 8)
        tile[ff][j] =
            ((const float*)(ws + (size_t)(b * 32 + ff) * SLAB_US + O_OFF))[t0 + j];
    __syncthreads();
#pragma unroll
    for (int jj = a; jj < 32; jj += 8)
        out[b * (T_LEN * F_CH) + (t0 + jj) * F_CH + j] = tile[j][jj];
}

// ---------------------------------------------------------------------------
extern "C" void kernel_launch(void* const* d_in, const int* in_sizes, int n_in,
                              void* d_out, int out_size, void* d_ws, size_t ws_size,
                              hipStream_t stream) {
    const float* X = (const float*)d_in[0];
    float* out = (float*)d_out;
    (void)in_sizes; (void)n_in; (void)out_size; (void)ws_size;
    unsigned short* ws = (unsigned short*)d_ws;

    k0_stage<<<dim3(1024), dim3(256), 0, stream>>>(X, ws);
    corr1d_mfma_kernel<<<dim3(1024), dim3(256), 0, stream>>>(ws);
    k2_out<<<dim3(4096), dim3(256), 0, stream>>>(ws, out);
}